// Round 1
// baseline (264.049 us; speedup 1.0000x reference)
//
#include <hip/hip_runtime.h>
#include <math.h>

// Blinn-Phong shading, N=4194304 elements of (light,normal,view) 3-vectors.
// Memory-bound streaming kernel: 36 B in + 12 B out per element.
// AoS layout -> stage via LDS with coalesced float4 loads/stores.

#define BLOCK 256
#define EPS 1e-12f

__global__ __launch_bounds__(BLOCK) void blinn_phong_kernel(
    const float* __restrict__ in,   // (n, 3, 3)
    const float* __restrict__ kd,   // (3,)
    const float* __restrict__ ks,   // (3,)
    const float* __restrict__ pp,   // (1,)
    float* __restrict__ out,        // (n, 3)
    int n)
{
    __shared__ float s_in[BLOCK * 9];   // 36 KB
    __shared__ float s_out[BLOCK * 3];  // 3 KB

    const int bid = blockIdx.x;
    const int tid = threadIdx.x;

    // ---- coalesced global->LDS stage: 2304 float4 per block, 9 per thread ----
    const long long blk_elem0 = (long long)bid * BLOCK;
    const float4* gin = (const float4*)(in + blk_elem0 * 9);
    float4* s4 = (float4*)s_in;
    const long long total4 = ((long long)n * 9) >> 2;   // n*9 divisible by 4 here
    const long long base4 = blk_elem0 * 9 / 4;          // 2304 * bid
#pragma unroll
    for (int i = 0; i < 9; ++i) {
        long long g = base4 + tid + i * BLOCK;
        if (g < total4) s4[tid + i * BLOCK] = gin[tid + i * BLOCK];
    }
    __syncthreads();

    // ---- per-element math from LDS (stride-9 float reads: 2-way bank alias, free) ----
    const long long elem = blk_elem0 + tid;
    if (elem < n) {
        const float* e = s_in + tid * 9;
        float Lx = e[0], Ly = e[1], Lz = e[2];
        float Nx = e[3], Ny = e[4], Nz = e[5];
        float Vx = e[6], Vy = e[7], Vz = e[8];

        float kd0 = kd[0], kd1 = kd[1], kd2 = kd[2];
        float ks0 = ks[0], ks1 = ks[1], ks2 = ks[2];
        float p = pp[0];

        // diffuse term
        float ln = fmaxf(0.0f, Lx * Nx + Ly * Ny + Lz * Nz);

        // half vector
        float hx = Lx + Vx, hy = Ly + Vy, hz = Lz + Vz;
        float hh = hx * hx + hy * hy + hz * hz;
        float nrm = fmaxf(sqrtf(hh), EPS);
        float inv = 1.0f / nrm;

        float nh = fmaxf(0.0f, (Nx * hx + Ny * hy + Nz * hz) * inv);
        float spec = powf(nh, p);

        s_out[tid * 3 + 0] = ks0 * spec + kd0 * ln;
        s_out[tid * 3 + 1] = ks1 * spec + kd1 * ln;
        s_out[tid * 3 + 2] = ks2 * spec + kd2 * ln;
    }
    __syncthreads();

    // ---- coalesced LDS->global store: 192 float4 per block ----
    float4* gout = (float4*)(out + blk_elem0 * 3);
    const float4* so4 = (const float4*)s_out;
    const long long out_total4 = ((long long)n * 3) >> 2;
    const long long out_base4 = blk_elem0 * 3 / 4;      // 192 * bid
    if (tid < 192) {
        long long g = out_base4 + tid;
        if (g < out_total4) gout[tid] = so4[tid];
    }
}

extern "C" void kernel_launch(void* const* d_in, const int* in_sizes, int n_in,
                              void* d_out, int out_size, void* d_ws, size_t ws_size,
                              hipStream_t stream) {
    const float* in = (const float*)d_in[0];
    const float* kd = (const float*)d_in[1];
    const float* ks = (const float*)d_in[2];
    const float* pp = (const float*)d_in[3];
    float* out = (float*)d_out;

    int n = in_sizes[0] / 9;
    int grid = (n + BLOCK - 1) / BLOCK;
    blinn_phong_kernel<<<grid, BLOCK, 0, stream>>>(in, kd, ks, pp, out, n);
}

// Round 2
// 227.997 us; speedup vs baseline: 1.1581x; 1.1581x over previous
//
#include <hip/hip_runtime.h>
#include <math.h>

// Blinn-Phong shading, N=4194304 elements of (light,normal,view) 3-vectors.
// Memory-bound streaming kernel: 36 B in + 12 B out per element -> 201 MB total,
// ~32 us floor at 6.3 TB/s.
// AoS layout -> stage via LDS with coalesced float4 loads/stores.
// R1 bug fixed: stage exactly 576 float4 per 256-elem block (was 2304 -> 2x HBM overfetch).

#define BLOCK 256
#define EPS 1e-12f

__global__ __launch_bounds__(BLOCK) void blinn_phong_kernel(
    const float* __restrict__ in,   // (n, 3, 3)
    const float* __restrict__ kd,   // (3,)
    const float* __restrict__ ks,   // (3,)
    const float* __restrict__ pp,   // (1,)
    float* __restrict__ out,        // (n, 3)
    int n)
{
    __shared__ float s_in[BLOCK * 9];   // 9 KB
    __shared__ float s_out[BLOCK * 3];  // 3 KB

    const int bid = blockIdx.x;
    const int tid = threadIdx.x;

    // ---- coalesced global->LDS stage: 576 float4 per block ----
    const long long blk_elem0 = (long long)bid * BLOCK;
    const float4* gin = (const float4*)(in + blk_elem0 * 9);
    float4* s4 = (float4*)s_in;
    const long long total4 = ((long long)n * 9) >> 2;   // n*9 divisible by 4 here
    const long long base4 = blk_elem0 * 9 / 4;          // 576 * bid
    if (base4 + tid < total4)       s4[tid]       = gin[tid];
    if (base4 + tid + 256 < total4) s4[tid + 256] = gin[tid + 256];
    if (tid < 64 && base4 + tid + 512 < total4) s4[tid + 512] = gin[tid + 512];
    __syncthreads();

    // ---- per-element math from LDS (stride-9 float reads: 2-way bank alias, free) ----
    const long long elem = blk_elem0 + tid;
    if (elem < n) {
        const float* e = s_in + tid * 9;
        float Lx = e[0], Ly = e[1], Lz = e[2];
        float Nx = e[3], Ny = e[4], Nz = e[5];
        float Vx = e[6], Vy = e[7], Vz = e[8];

        float kd0 = kd[0], kd1 = kd[1], kd2 = kd[2];
        float ks0 = ks[0], ks1 = ks[1], ks2 = ks[2];
        float p = pp[0];

        // diffuse term
        float ln = fmaxf(0.0f, Lx * Nx + Ly * Ny + Lz * Nz);

        // half vector
        float hx = Lx + Vx, hy = Ly + Vy, hz = Lz + Vz;
        float hh = hx * hx + hy * hy + hz * hz;
        float nrm = fmaxf(sqrtf(hh), EPS);
        float inv = 1.0f / nrm;

        float nh = fmaxf(0.0f, (Nx * hx + Ny * hy + Nz * hz) * inv);
        float spec = powf(nh, p);

        s_out[tid * 3 + 0] = ks0 * spec + kd0 * ln;
        s_out[tid * 3 + 1] = ks1 * spec + kd1 * ln;
        s_out[tid * 3 + 2] = ks2 * spec + kd2 * ln;
    }
    __syncthreads();

    // ---- coalesced LDS->global store: 192 float4 per block ----
    float4* gout = (float4*)(out + blk_elem0 * 3);
    const float4* so4 = (const float4*)s_out;
    const long long out_total4 = ((long long)n * 3) >> 2;
    const long long out_base4 = blk_elem0 * 3 / 4;      // 192 * bid
    if (tid < 192) {
        long long g = out_base4 + tid;
        if (g < out_total4) gout[tid] = so4[tid];
    }
}

extern "C" void kernel_launch(void* const* d_in, const int* in_sizes, int n_in,
                              void* d_out, int out_size, void* d_ws, size_t ws_size,
                              hipStream_t stream) {
    const float* in = (const float*)d_in[0];
    const float* kd = (const float*)d_in[1];
    const float* ks = (const float*)d_in[2];
    const float* pp = (const float*)d_in[3];
    float* out = (float*)d_out;

    int n = in_sizes[0] / 9;
    int grid = (n + BLOCK - 1) / BLOCK;
    blinn_phong_kernel<<<grid, BLOCK, 0, stream>>>(in, kd, ks, pp, out, n);
}